// Round 1
// baseline (2281.834 us; speedup 1.0000x reference)
//
#include <hip/hip_runtime.h>

#define E_EDGES 500000
#define N_NODES 30000
#define H_DIM   256

typedef float  floatx4 __attribute__((ext_vector_type(4)));
typedef short  shortx4 __attribute__((ext_vector_type(4)));
typedef short  shortx8 __attribute__((ext_vector_type(8)));
typedef __bf16 bf16x8  __attribute__((ext_vector_type(8)));

__device__ inline short f2bf(float f) {
    unsigned u = __builtin_bit_cast(unsigned, f);
    u += 0x7fffu + ((u >> 16) & 1u);        // round-to-nearest-even
    return (short)(u >> 16);
}
__device__ inline float bf2f(short s) {
    unsigned u = ((unsigned)(unsigned short)s) << 16;
    return __builtin_bit_cast(float, u);
}

// ---------------------------------------------------------------------------
// Reformat W_up / W_hidden into MFMA B-fragment-major bf16:
// for matrix [K=256][N=256]: frag16B index g = (ks*16 + nt)*64 + lane,
// holding W[ks*32 + (lane>>4)*8 + j][nt*16 + (lane&15)], j = 0..7.
// ---------------------------------------------------------------------------
__global__ __launch_bounds__(256) void prep_weights(
    const float* __restrict__ wup, const float* __restrict__ whid,
    short* __restrict__ wfrag)
{
    int g   = blockIdx.x * 256 + threadIdx.x;   // 0..65535
    int mat = g >> 13;                          // 8 matrices (2 branches x 4 layers)
    int grp = g & 8191;
    int a = mat >> 2, lay = mat & 3;
    const float* src = (lay == 0) ? (wup + a * 65536)
                                  : (whid + (a * 3 + lay - 1) * 65536);
    int ks  = grp >> 10;
    int rem = grp & 1023;
    int ntg = rem >> 6;
    int lane = rem & 63;
    int q = lane >> 4, c = lane & 15;
    int col = ntg * 16 + c;
    int k0  = ks * 32 + q * 8;
    shortx8 v;
#pragma unroll
    for (int j = 0; j < 8; j++) v[j] = f2bf(src[(k0 + j) * 256 + col]);
    ((shortx8*)wfrag)[g] = v;
}

// ---------------------------------------------------------------------------
// Edge phase: one wave per edge, lane handles 4 features.
// msg = (rbf[e] @ W_rbf) * x[e]; atomicAdd into h[idx[e]].
// ---------------------------------------------------------------------------
__global__ __launch_bounds__(256) void edge_scatter(
    const float* __restrict__ x, const float* __restrict__ rbf,
    const int* __restrict__ idx, const float* __restrict__ wrbf,
    float* __restrict__ h)
{
    int e = blockIdx.x * 4 + (threadIdx.x >> 6);
    if (e >= E_EDGES) return;
    int lane = threadIdx.x & 63;

    float r[6];
#pragma unroll
    for (int k = 0; k < 6; k++) r[k] = rbf[e * 6 + k];   // wave-broadcast loads
    int node = idx[e];

    const floatx4* wr4 = (const floatx4*)wrbf;           // [6][64] float4
    floatx4 p = r[0] * wr4[lane];
#pragma unroll
    for (int k = 1; k < 6; k++) p += r[k] * wr4[k * 64 + lane];

    floatx4 xv = ((const floatx4*)x)[(size_t)e * 64 + lane];
    floatx4 m  = p * xv;

    float* hp = h + (size_t)node * H_DIM + lane * 4;
    atomicAdd(hp + 0, m.x);
    atomicAdd(hp + 1, m.y);
    atomicAdd(hp + 2, m.z);
    atomicAdd(hp + 3, m.w);
}

// ---------------------------------------------------------------------------
// Fused MLP: block = 64 rows, 4 waves; wave w owns output cols [w*64, w*64+64).
// Activations ping-pong in LDS (bf16, row stride 264 for bank balance).
// A-frags from LDS (m=lane&15, k=quad*8+j); B-frags straight from global
// fragment-major weights (L2-resident). Epilogue: bias + SiLU, bf16 writeback.
// ---------------------------------------------------------------------------
__global__ __launch_bounds__(256, 2) void mlp_kernel(
    const float* __restrict__ h, const short* __restrict__ wfrag,
    const float* __restrict__ bias, const float* __restrict__ wout,
    float* __restrict__ out)
{
    __shared__ __align__(16) short ylds[2][64 * 264];
    const int t = threadIdx.x;
    const int wave = t >> 6, lane = t & 63, q = lane >> 4, c15 = lane & 15;
    const int n0 = blockIdx.x * 64;
    const floatx4 fzero = {0.f, 0.f, 0.f, 0.f};

    for (int a = 0; a < 2; a++) {
        // stage h tile -> ylds[0] as bf16
#pragma unroll
        for (int j = 0; j < 16; j++) {
            int f = t + j * 256;            // float4 index within [64][64]
            int r = f >> 6, c4 = f & 63;
            floatx4 v = fzero;
            if (n0 + r < N_NODES) v = ((const floatx4*)h)[(size_t)(n0 + r) * 64 + c4];
            shortx4 s4 = { f2bf(v.x), f2bf(v.y), f2bf(v.z), f2bf(v.w) };
            *(shortx4*)&ylds[0][r * 264 + c4 * 4] = s4;
        }
        __syncthreads();

        int src = 0;
        for (int lay = 0; lay < 4; lay++) {     // 0 = up (no bias/act), 1..3 hidden
            const bf16x8* wf = (const bf16x8*)(wfrag + (size_t)(a * 4 + lay) * 65536);
            floatx4 acc[4][4];
#pragma unroll
            for (int mt = 0; mt < 4; mt++)
#pragma unroll
                for (int nt = 0; nt < 4; nt++) acc[mt][nt] = fzero;

#pragma unroll
            for (int ks = 0; ks < 8; ks++) {
                bf16x8 afr[4], bfr[4];
#pragma unroll
                for (int mt = 0; mt < 4; mt++)
                    afr[mt] = *(const bf16x8*)&ylds[src][(mt * 16 + c15) * 264 + ks * 32 + q * 8];
#pragma unroll
                for (int nt = 0; nt < 4; nt++)
                    bfr[nt] = wf[(ks * 16 + wave * 4 + nt) * 64 + lane];
#pragma unroll
                for (int mt = 0; mt < 4; mt++)
#pragma unroll
                    for (int nt = 0; nt < 4; nt++)
                        acc[mt][nt] = __builtin_amdgcn_mfma_f32_16x16x32_bf16(
                            afr[mt], bfr[nt], acc[mt][nt], 0, 0, 0);
            }

            int dst = 1 - src;
            float bv[4];
#pragma unroll
            for (int nt = 0; nt < 4; nt++)
                bv[nt] = (lay >= 1) ? bias[(a * 3 + lay - 1) * 256 + wave * 64 + nt * 16 + c15]
                                    : 0.0f;
#pragma unroll
            for (int mt = 0; mt < 4; mt++) {
#pragma unroll
                for (int nt = 0; nt < 4; nt++) {
#pragma unroll
                    for (int rg = 0; rg < 4; rg++) {
                        float v = acc[mt][nt][rg] + bv[nt];
                        if (lay >= 1) v = v / (1.0f + __expf(-v));   // SiLU
                        int row = mt * 16 + q * 4 + rg;              // D: row = quad*4+reg
                        int col = wave * 64 + nt * 16 + c15;         // D: col = lane&15
                        ylds[dst][row * 264 + col] = f2bf(v);
                    }
                }
            }
            __syncthreads();
            src = dst;
        }

        // out = y @ W_out[a]  (256 -> 1), wave w handles rows w*16..w*16+15
        {
            int r  = wave * 16 + (lane >> 2);
            int cq = lane & 3;
            float s = 0.0f;
#pragma unroll 16
            for (int c = cq * 64; c < cq * 64 + 64; c++)
                s += bf2f(ylds[src][r * 264 + c]) * wout[a * 256 + c];
            s += __shfl_xor(s, 1);
            s += __shfl_xor(s, 2);
            if (cq == 0 && n0 + r < N_NODES) out[a * N_NODES + n0 + r] = s;
        }
        __syncthreads();
    }
}

// ---------------------------------------------------------------------------
extern "C" void kernel_launch(void* const* d_in, const int* in_sizes, int n_in,
                              void* d_out, int out_size, void* d_ws, size_t ws_size,
                              hipStream_t stream)
{
    const float* x    = (const float*)d_in[0];
    const float* rbf  = (const float*)d_in[1];
    const int*   idx  = (const int*)d_in[2];
    const float* wrbf = (const float*)d_in[4];
    const float* wup  = (const float*)d_in[5];
    const float* whid = (const float*)d_in[6];
    const float* bias = (const float*)d_in[7];
    const float* wout = (const float*)d_in[8];
    float* out = (float*)d_out;

    float* h     = (float*)d_ws;                      // 30000*256 fp32 = 30.72 MB
    short* wfrag = (short*)((char*)d_ws + (size_t)N_NODES * H_DIM * sizeof(float));

    hipMemsetAsync(h, 0, (size_t)N_NODES * H_DIM * sizeof(float), stream);
    prep_weights<<<256, 256, 0, stream>>>(wup, whid, wfrag);
    edge_scatter<<<E_EDGES / 4, 256, 0, stream>>>(x, rbf, idx, wrbf, h);
    mlp_kernel<<<(N_NODES + 63) / 64, 256, 0, stream>>>(h, wfrag, bias, wout, out);
}

// Round 2
// 876.511 us; speedup vs baseline: 2.6033x; 2.6033x over previous
//
#include <hip/hip_runtime.h>

#define E_EDGES 500000
#define N_NODES 30000
#define H_DIM   256

typedef float  floatx4 __attribute__((ext_vector_type(4)));
typedef short  shortx4 __attribute__((ext_vector_type(4)));
typedef short  shortx8 __attribute__((ext_vector_type(8)));
typedef __bf16 bf16x8  __attribute__((ext_vector_type(8)));

__device__ inline short f2bf(float f) {
    unsigned u = __builtin_bit_cast(unsigned, f);
    u += 0x7fffu + ((u >> 16) & 1u);        // round-to-nearest-even
    return (short)(u >> 16);
}
__device__ inline float bf2f(short s) {
    unsigned u = ((unsigned)(unsigned short)s) << 16;
    return __builtin_bit_cast(float, u);
}

// ---------------------------------------------------------------------------
// Reformat W_up / W_hidden into MFMA B-fragment-major bf16.
// ---------------------------------------------------------------------------
__global__ __launch_bounds__(256) void prep_weights(
    const float* __restrict__ wup, const float* __restrict__ whid,
    short* __restrict__ wfrag)
{
    int g   = blockIdx.x * 256 + threadIdx.x;   // 0..65535
    int mat = g >> 13;
    int grp = g & 8191;
    int a = mat >> 2, lay = mat & 3;
    const float* src = (lay == 0) ? (wup + a * 65536)
                                  : (whid + (a * 3 + lay - 1) * 65536);
    int ks  = grp >> 10;
    int rem = grp & 1023;
    int ntg = rem >> 6;
    int lane = rem & 63;
    int q = lane >> 4, c = lane & 15;
    int col = ntg * 16 + c;
    int k0  = ks * 32 + q * 8;
    shortx8 v;
#pragma unroll
    for (int j = 0; j < 8; j++) v[j] = f2bf(src[(k0 + j) * 256 + col]);
    ((shortx8*)wfrag)[g] = v;
}

// ---------------------------------------------------------------------------
// CSR build: histogram -> exclusive scan -> id scatter.
// ---------------------------------------------------------------------------
__global__ __launch_bounds__(256) void hist_kernel(
    const int* __restrict__ idx, int* __restrict__ counts)
{
    int e = blockIdx.x * 256 + threadIdx.x;
    if (e < E_EDGES) atomicAdd(&counts[idx[e]], 1);
}

__global__ __launch_bounds__(1024) void scan_kernel(
    const int* __restrict__ counts, int* __restrict__ offsets,
    int* __restrict__ cursor)
{
    const int t = threadIdx.x;                  // 1024 threads, chunk = 30
    const int lane = t & 63, wave = t >> 6;
    const int base = t * 30;
    int local[30];
    int s = 0;
#pragma unroll
    for (int j = 0; j < 30; j++) {
        int c = (base + j < N_NODES) ? counts[base + j] : 0;
        local[j] = s;                           // exclusive within chunk
        s += c;
    }
    // inclusive wave scan of s
    int incl = s;
#pragma unroll
    for (int d = 1; d < 64; d <<= 1) {
        int v = __shfl_up(incl, d);
        if (lane >= d) incl += v;
    }
    __shared__ int part[16];
    if (lane == 63) part[wave] = incl;
    __syncthreads();
    if (t == 0) {
        int run = 0;
#pragma unroll
        for (int k = 0; k < 16; k++) { int v = part[k]; part[k] = run; run += v; }
    }
    __syncthreads();
    int excl = part[wave] + incl - s;           // exclusive base for this thread
#pragma unroll
    for (int j = 0; j < 30; j++) {
        int n = base + j;
        if (n < N_NODES) { offsets[n] = excl + local[j]; cursor[n] = excl + local[j]; }
    }
    if (t == 1023) offsets[N_NODES] = excl + s; // grand total = E_EDGES
}

__global__ __launch_bounds__(256) void scatter_ids(
    const int* __restrict__ idx, int* __restrict__ cursor,
    int* __restrict__ edge_list)
{
    int e = blockIdx.x * 256 + threadIdx.x;
    if (e >= E_EDGES) return;
    int pos = atomicAdd(&cursor[idx[e]], 1);
    edge_list[pos] = e;
}

// ---------------------------------------------------------------------------
// Gather: one wave per node. Registers hold W_rbf; per edge read rbf row
// (broadcast) + x row (coalesced 1KB), accumulate, one float4 store per lane.
// No fp atomics -> deterministic, full-line writes.
// ---------------------------------------------------------------------------
__global__ __launch_bounds__(256) void gather_nodes(
    const float* __restrict__ x, const float* __restrict__ rbf,
    const int* __restrict__ edge_list, const int* __restrict__ offsets,
    const float* __restrict__ wrbf, float* __restrict__ h)
{
    int node = blockIdx.x * 4 + (threadIdx.x >> 6);
    if (node >= N_NODES) return;
    int lane = threadIdx.x & 63;

    const floatx4* wr4 = (const floatx4*)wrbf;   // [6][64] float4
    floatx4 wr[6];
#pragma unroll
    for (int k = 0; k < 6; k++) wr[k] = wr4[k * 64 + lane];

    int beg = offsets[node], end = offsets[node + 1];
    floatx4 acc = {0.f, 0.f, 0.f, 0.f};
    for (int j = beg; j < end; j++) {
        int e = edge_list[j];
        float r0 = rbf[e * 6 + 0], r1 = rbf[e * 6 + 1], r2 = rbf[e * 6 + 2];
        float r3 = rbf[e * 6 + 3], r4 = rbf[e * 6 + 4], r5 = rbf[e * 6 + 5];
        floatx4 xv = ((const floatx4*)x)[(size_t)e * 64 + lane];
        floatx4 p = r0 * wr[0] + r1 * wr[1] + r2 * wr[2]
                  + r3 * wr[3] + r4 * wr[4] + r5 * wr[5];
        acc += p * xv;
    }
    ((floatx4*)h)[(size_t)node * 64 + lane] = acc;
}

// ---------------------------------------------------------------------------
// Fused MLP (unchanged from round 1): block = 64 rows, 4 waves.
// ---------------------------------------------------------------------------
__global__ __launch_bounds__(256, 2) void mlp_kernel(
    const float* __restrict__ h, const short* __restrict__ wfrag,
    const float* __restrict__ bias, const float* __restrict__ wout,
    float* __restrict__ out)
{
    __shared__ __align__(16) short ylds[2][64 * 264];
    const int t = threadIdx.x;
    const int wave = t >> 6, lane = t & 63, q = lane >> 4, c15 = lane & 15;
    const int n0 = blockIdx.x * 64;
    const floatx4 fzero = {0.f, 0.f, 0.f, 0.f};

    for (int a = 0; a < 2; a++) {
#pragma unroll
        for (int j = 0; j < 16; j++) {
            int f = t + j * 256;
            int r = f >> 6, c4 = f & 63;
            floatx4 v = fzero;
            if (n0 + r < N_NODES) v = ((const floatx4*)h)[(size_t)(n0 + r) * 64 + c4];
            shortx4 s4 = { f2bf(v.x), f2bf(v.y), f2bf(v.z), f2bf(v.w) };
            *(shortx4*)&ylds[0][r * 264 + c4 * 4] = s4;
        }
        __syncthreads();

        int src = 0;
        for (int lay = 0; lay < 4; lay++) {
            const bf16x8* wf = (const bf16x8*)(wfrag + (size_t)(a * 4 + lay) * 65536);
            floatx4 acc[4][4];
#pragma unroll
            for (int mt = 0; mt < 4; mt++)
#pragma unroll
                for (int nt = 0; nt < 4; nt++) acc[mt][nt] = fzero;

#pragma unroll
            for (int ks = 0; ks < 8; ks++) {
                bf16x8 afr[4], bfr[4];
#pragma unroll
                for (int mt = 0; mt < 4; mt++)
                    afr[mt] = *(const bf16x8*)&ylds[src][(mt * 16 + c15) * 264 + ks * 32 + q * 8];
#pragma unroll
                for (int nt = 0; nt < 4; nt++)
                    bfr[nt] = wf[(ks * 16 + wave * 4 + nt) * 64 + lane];
#pragma unroll
                for (int mt = 0; mt < 4; mt++)
#pragma unroll
                    for (int nt = 0; nt < 4; nt++)
                        acc[mt][nt] = __builtin_amdgcn_mfma_f32_16x16x32_bf16(
                            afr[mt], bfr[nt], acc[mt][nt], 0, 0, 0);
            }

            int dst = 1 - src;
            float bv[4];
#pragma unroll
            for (int nt = 0; nt < 4; nt++)
                bv[nt] = (lay >= 1) ? bias[(a * 3 + lay - 1) * 256 + wave * 64 + nt * 16 + c15]
                                    : 0.0f;
#pragma unroll
            for (int mt = 0; mt < 4; mt++) {
#pragma unroll
                for (int nt = 0; nt < 4; nt++) {
#pragma unroll
                    for (int rg = 0; rg < 4; rg++) {
                        float v = acc[mt][nt][rg] + bv[nt];
                        if (lay >= 1) v = v / (1.0f + __expf(-v));   // SiLU
                        int row = mt * 16 + q * 4 + rg;
                        int col = wave * 64 + nt * 16 + c15;
                        ylds[dst][row * 264 + col] = f2bf(v);
                    }
                }
            }
            __syncthreads();
            src = dst;
        }

        {
            int r  = wave * 16 + (lane >> 2);
            int cq = lane & 3;
            float s = 0.0f;
#pragma unroll 16
            for (int c = cq * 64; c < cq * 64 + 64; c++)
                s += bf2f(ylds[src][r * 264 + c]) * wout[a * 256 + c];
            s += __shfl_xor(s, 1);
            s += __shfl_xor(s, 2);
            if (cq == 0 && n0 + r < N_NODES) out[a * N_NODES + n0 + r] = s;
        }
        __syncthreads();
    }
}

// ---------------------------------------------------------------------------
extern "C" void kernel_launch(void* const* d_in, const int* in_sizes, int n_in,
                              void* d_out, int out_size, void* d_ws, size_t ws_size,
                              hipStream_t stream)
{
    const float* x    = (const float*)d_in[0];
    const float* rbf  = (const float*)d_in[1];
    const int*   idx  = (const int*)d_in[2];
    const float* wrbf = (const float*)d_in[4];
    const float* wup  = (const float*)d_in[5];
    const float* whid = (const float*)d_in[6];
    const float* bias = (const float*)d_in[7];
    const float* wout = (const float*)d_in[8];
    float* out = (float*)d_out;

    char* ws = (char*)d_ws;
    float* h         = (float*)ws;                                   ws += (size_t)N_NODES * H_DIM * sizeof(float);
    short* wfrag     = (short*)ws;                                   ws += (size_t)8 * 65536 * sizeof(short);
    int*   counts    = (int*)ws;                                     ws += (size_t)N_NODES * sizeof(int);
    int*   offsets   = (int*)ws;                                     ws += (size_t)(N_NODES + 1) * sizeof(int);
    int*   cursor    = (int*)ws;                                     ws += (size_t)N_NODES * sizeof(int);
    int*   edge_list = (int*)ws;

    hipMemsetAsync(counts, 0, (size_t)N_NODES * sizeof(int), stream);
    prep_weights<<<256, 256, 0, stream>>>(wup, whid, wfrag);
    hist_kernel<<<(E_EDGES + 255) / 256, 256, 0, stream>>>(idx, counts);
    scan_kernel<<<1, 1024, 0, stream>>>(counts, offsets, cursor);
    scatter_ids<<<(E_EDGES + 255) / 256, 256, 0, stream>>>(idx, cursor, edge_list);
    gather_nodes<<<(N_NODES + 3) / 4, 256, 0, stream>>>(x, rbf, edge_list, offsets, wrbf, h);
    mlp_kernel<<<(N_NODES + 63) / 64, 256, 0, stream>>>(h, wfrag, bias, wout, out);
}